// Round 3
// baseline (300.666 us; speedup 1.0000x reference)
//
#include <hip/hip_runtime.h>
#include <hip/hip_bf16.h>
#include <stdint.h>

// Problem constants
#define M_DIM 8192   // B*S = 4*2048
#define N_C   4096   // contraction dim (N in reference)
#define K_OUT 4096   // output features (K in reference)
#define NGRP  32
#define NT    (N_C / 32)   // 128 K-tiles of 32

typedef __attribute__((ext_vector_type(8))) short bf16x8;
typedef __attribute__((ext_vector_type(4))) float f32x4;

// fp32 -> bf16, round-to-nearest-even (inputs are finite)
__device__ __forceinline__ unsigned short f2b(float f) {
  unsigned u = __float_as_uint(f);
  return (unsigned short)((u + 0x7fffu + ((u >> 16) & 1u)) >> 16);
}

__device__ __forceinline__ void gload_lds16(const void* g, void* l) {
  __builtin_amdgcn_global_load_lds(
      (const __attribute__((address_space(1))) void*)g,
      (__attribute__((address_space(3))) void*)l,
      16, 0, 0);
}

// ---- x fp32 -> bf16 ----
__global__ void convert_x_kernel(const float* __restrict__ x,
                                 unsigned short* __restrict__ xb) {
  const int total = (M_DIM * N_C) / 8;
  const int stride = gridDim.x * blockDim.x;
  for (int i = blockIdx.x * blockDim.x + threadIdx.x; i < total; i += stride) {
    const float4* p = (const float4*)(x + (size_t)i * 8);
    float4 a = p[0];
    float4 b = p[1];
    union { unsigned short u[8]; uint4 v; } o;
    o.u[0] = f2b(a.x); o.u[1] = f2b(a.y); o.u[2] = f2b(a.z); o.u[3] = f2b(a.w);
    o.u[4] = f2b(b.x); o.u[5] = f2b(b.y); o.u[6] = f2b(b.z); o.u[7] = f2b(b.w);
    *(uint4*)(xb + (size_t)i * 8) = o.v;
  }
}

// ---- W dequant -> bf16 [K_OUT][N_C] ----
__global__ void dequant_w_kernel(const int* __restrict__ Wq,
                                 const float* __restrict__ scales,
                                 const float* __restrict__ zeros,
                                 const float* __restrict__ mu1,
                                 const float* __restrict__ mu2,
                                 unsigned short* __restrict__ wb) {
  const int total = (K_OUT * N_C) / 8;
  const int stride = gridDim.x * blockDim.x;
  for (int i = blockIdx.x * blockDim.x + threadIdx.x; i < total; i += stride) {
    const int k  = i >> 9;
    const int nc = (i & 511) << 3;
    const int g  = nc >> 7;
    const float s = scales[k * NGRP + g];
    const float z = zeros[k * NGRP + g];
    const float f  = s * mu2[k];
    const float zf = z * f;
    const int4* q4 = (const int4*)(Wq + (size_t)k * N_C + nc);
    int4 q0 = q4[0], q1 = q4[1];
    const float4* m4 = (const float4*)(mu1 + nc);
    float4 m0 = m4[0], m1 = m4[1];
    union { unsigned short u[8]; uint4 v; } o;
    o.u[0] = f2b(((float)q0.x * f - zf) * m0.x);
    o.u[1] = f2b(((float)q0.y * f - zf) * m0.y);
    o.u[2] = f2b(((float)q0.z * f - zf) * m0.z);
    o.u[3] = f2b(((float)q0.w * f - zf) * m0.w);
    o.u[4] = f2b(((float)q1.x * f - zf) * m1.x);
    o.u[5] = f2b(((float)q1.y * f - zf) * m1.y);
    o.u[6] = f2b(((float)q1.z * f - zf) * m1.z);
    o.u[7] = f2b(((float)q1.w * f - zf) * m1.w);
    *(uint4*)(wb + (size_t)i * 8) = o.v;
  }
}

// ---- Deep-pipelined bf16 GEMM: out[m][n] = sum_k Xb[m][k]*Wb[n][k] + bias[n]
// 256x256 tile, BK=32, 8 waves (2Mx4N, per-wave 128x64), 4 LDS buffers
// (128 KB), prefetch depth 3, counted vmcnt(8), one s_barrier per K-tile,
// XOR-swizzled LDS (0 bank conflicts, verified R2).
// R3 change: ds_reads in MFMA-consumption order so the compiler's counted
// lgkmcnt starts the MFMA stream after ~2 reads instead of 9 (DS||MFMA
// overlap within each wave).
__global__ __launch_bounds__(512) void gemm_bf16_kernel(
    const unsigned short* __restrict__ Xb,   // [M_DIM][N_C] bf16
    const unsigned short* __restrict__ Wb,   // [K_OUT][N_C] bf16
    const float* __restrict__ bias,          // [K_OUT]
    float* __restrict__ out) {               // [M_DIM][K_OUT]
  __shared__ unsigned short smem[65536];     // 128 KiB: 4 bufs x 32 KiB

  // XCD-aware bijective swizzle: 512 blocks, 8 XCDs, 64 per XCD
  const int bid = blockIdx.x;
  const int swz = (bid & 7) * 64 + (bid >> 3);
  const int n0 = (swz & 15) * 256;   // output-feature tile (16 tiles)
  const int m0 = (swz >> 4) * 256;   // row tile (32 tiles)

  const int tid = threadIdx.x;
  const int w   = tid >> 6;
  const int l   = tid & 63;
  const int wr  = w >> 2;     // 0..1 -> 128 rows each
  const int wc  = w & 3;      // 0..3 -> 64 cols each

  // ---- staging sources (pre-swizzled per-lane global addresses) ----
  const char* Xc = (const char*)Xb;
  const char* Wc = (const char*)Wb;
  const char* srcA[2];
  const char* srcB[2];
  int dstOff[2];
#pragma unroll
  for (int e = 0; e < 2; ++e) {
    const int P  = (e * 8 + w) * 1024 + l * 16;
    const int r  = P >> 6;
    const int sl = ((P >> 4) & 3) ^ ((r >> 1) & 3);
    srcA[e] = Xc + (size_t)(m0 + r) * (N_C * 2) + sl * 16;
    srcB[e] = Wc + (size_t)(n0 + r) * (N_C * 2) + sl * 16;
    dstOff[e] = (e * 8 + w) * 1024;   // wave-uniform LDS byte offset
  }

  // ---- swizzled ds_read offsets (ushort units, within one 32KB buffer) ----
  int offa[8], offb[4];
#pragma unroll
  for (int i = 0; i < 8; ++i) {
    const int r  = wr * 128 + i * 16 + (l & 15);
    const int sl = (l >> 4) ^ ((r >> 1) & 3);
    offa[i] = (r * 64 + sl * 16) >> 1;
  }
#pragma unroll
  for (int j = 0; j < 4; ++j) {
    const int r  = wc * 64 + j * 16 + (l & 15);
    const int sl = (l >> 4) ^ ((r >> 1) & 3);
    offb[j] = (16384 + r * 64 + sl * 16) >> 1;
  }

  f32x4 acc[8][4] = {};
  char* ldsc = (char*)smem;

#define STAGE(tt)                                                            \
  { const int sb = ((tt) & 3) * 32768; const size_t ko = (size_t)(tt) * 64;  \
    gload_lds16(srcA[0] + ko, ldsc + sb + dstOff[0]);                        \
    gload_lds16(srcA[1] + ko, ldsc + sb + dstOff[1]);                        \
    gload_lds16(srcB[0] + ko, ldsc + sb + 16384 + dstOff[0]);                \
    gload_lds16(srcB[1] + ko, ldsc + sb + 16384 + dstOff[1]); }

  // Prologue: stage tiles 0,1,2 (12 loads in flight)
  STAGE(0)
  STAGE(1)
  STAGE(2)

  // Contract (unchanged from R2): at top of iteration t, outstanding vmem =
  // stages of t+1,t+2 (8 loads) -> vmcnt(8) proves tile t landed; barrier
  // proves it for all waves. stage(t+3) overwrites buf[(t-1)&3], whose reads
  // were drained (data-dep before MFMAs) before every wave passed this
  // iteration's barrier.
  // Read order matches MFMA consumption: bf0,af0-3,bf1,bf2,bf3,af4-7.
#define KSTEP(VMSTR, tt, DOSTAGE)                                            \
  { asm volatile("s_waitcnt vmcnt(" VMSTR ")\n\ts_barrier" ::: "memory");    \
    const unsigned short* bp = smem + ((tt) & 3) * 16384;                    \
    bf16x8 af[8]; bf16x8 bfv[4];                                             \
    bfv[0] = *(const bf16x8*)(bp + offb[0]);                                 \
    af[0]  = *(const bf16x8*)(bp + offa[0]);                                 \
    af[1]  = *(const bf16x8*)(bp + offa[1]);                                 \
    af[2]  = *(const bf16x8*)(bp + offa[2]);                                 \
    af[3]  = *(const bf16x8*)(bp + offa[3]);                                 \
    bfv[1] = *(const bf16x8*)(bp + offb[1]);                                 \
    bfv[2] = *(const bf16x8*)(bp + offb[2]);                                 \
    bfv[3] = *(const bf16x8*)(bp + offb[3]);                                 \
    af[4]  = *(const bf16x8*)(bp + offa[4]);                                 \
    af[5]  = *(const bf16x8*)(bp + offa[5]);                                 \
    af[6]  = *(const bf16x8*)(bp + offa[6]);                                 \
    af[7]  = *(const bf16x8*)(bp + offa[7]);                                 \
    if (DOSTAGE) STAGE((tt) + 3)                                             \
    __builtin_amdgcn_s_setprio(1);                                           \
    _Pragma("unroll") for (int i = 0; i < 4; ++i)                            \
      acc[i][0] = __builtin_amdgcn_mfma_f32_16x16x32_bf16(af[i], bfv[0], acc[i][0], 0, 0, 0); \
    _Pragma("unroll") for (int i = 0; i < 4; ++i)                            \
      acc[i][1] = __builtin_amdgcn_mfma_f32_16x16x32_bf16(af[i], bfv[1], acc[i][1], 0, 0, 0); \
    _Pragma("unroll") for (int i = 0; i < 4; ++i)                            \
      acc[i][2] = __builtin_amdgcn_mfma_f32_16x16x32_bf16(af[i], bfv[2], acc[i][2], 0, 0, 0); \
    _Pragma("unroll") for (int i = 0; i < 4; ++i)                            \
      acc[i][3] = __builtin_amdgcn_mfma_f32_16x16x32_bf16(af[i], bfv[3], acc[i][3], 0, 0, 0); \
    _Pragma("unroll") for (int j = 0; j < 4; ++j)                            \
      _Pragma("unroll") for (int i = 4; i < 8; ++i)                          \
        acc[i][j] = __builtin_amdgcn_mfma_f32_16x16x32_bf16(af[i], bfv[j], acc[i][j], 0, 0, 0); \
    __builtin_amdgcn_s_setprio(0); }

#pragma unroll 1
  for (int kt = 0; kt < NT - 3; ++kt) KSTEP("8", kt, 1)
  KSTEP("8", NT - 3, 0)
  KSTEP("4", NT - 2, 0)
  KSTEP("0", NT - 1, 0)

#undef KSTEP
#undef STAGE

  // Epilogue: C/D layout col=lane&15, row=(lane>>4)*4+reg (verified R1)
#pragma unroll
  for (int j = 0; j < 4; ++j) {
    const int col = n0 + wc * 64 + j * 16 + (l & 15);
    const float bv = bias[col];
#pragma unroll
    for (int i = 0; i < 8; ++i) {
      const int row = m0 + wr * 128 + i * 16 + (l >> 4) * 4;
#pragma unroll
      for (int rr = 0; rr < 4; ++rr)
        out[(size_t)(row + rr) * K_OUT + col] = acc[i][j][rr] + bv;
    }
  }
}

extern "C" void kernel_launch(void* const* d_in, const int* in_sizes, int n_in,
                              void* d_out, int out_size, void* d_ws, size_t ws_size,
                              hipStream_t stream) {
  const float* x      = (const float*)d_in[0];
  const int*   Wq     = (const int*)d_in[1];
  const float* scales = (const float*)d_in[2];
  const float* zeros  = (const float*)d_in[3];
  const float* mu1    = (const float*)d_in[4];
  const float* mu2    = (const float*)d_in[5];
  const float* bias   = (const float*)d_in[6];
  float* out = (float*)d_out;

  unsigned short* xb = (unsigned short*)d_ws;
  unsigned short* wb = xb + (size_t)M_DIM * N_C;

  convert_x_kernel<<<2048, 256, 0, stream>>>(x, xb);
  dequant_w_kernel<<<2048, 256, 0, stream>>>(Wq, scales, zeros, mu1, mu2, wb);

  dim3 grid((M_DIM / 256) * (K_OUT / 256));   // 512 blocks
  gemm_bf16_kernel<<<grid, 512, 0, stream>>>(xb, wb, bias, out);
}